// Round 1
// baseline (612.774 us; speedup 1.0000x reference)
//
#include <hip/hip_runtime.h>
#include <math.h>

#define Bn 4
#define Cn 64
#define Ln 4096
#define CQ 16
#define NH 4
#define NB 32
#define EPSV 1e-5f
#define CH 128

// workspace layout in 4-byte units
#define OFF_Q    0
#define OFF_K    (OFF_Q + Bn*Ln*CQ)
#define OFF_V    (OFF_K + Bn*Ln*CQ)
#define OFF_ACC  (OFF_V + Bn*Ln*Cn)
#define OFF_Y    (OFF_ACC + Bn*Ln*Cn)
#define OFF_CNT  (OFF_Y + Bn*Cn*Ln)
#define OFF_ST   (OFF_CNT + Bn*NH*NB)
#define OFF_CUR  (OFF_ST + Bn*NH*NB)
#define OFF_MEM  (OFF_CUR + Bn*NH*NB)
#define OFF_MEAN (OFF_MEM + Bn*NH*Ln)
#define OFF_ISTD (OFF_MEAN + Cn)

__global__ void qkv_kernel(const float* __restrict__ x,
                           const float* __restrict__ Wq, const float* __restrict__ bq,
                           const float* __restrict__ Wk, const float* __restrict__ bk,
                           const float* __restrict__ Wv, const float* __restrict__ bv,
                           float* __restrict__ qo, float* __restrict__ ko,
                           float* __restrict__ vo) {
    __shared__ float sWq[CQ*Cn], sWk[CQ*Cn], sWv[Cn*Cn];
    __shared__ float sbq[CQ], sbk[CQ], sbv[Cn];
    int tid = threadIdx.x;
    for (int t = tid; t < CQ*Cn; t += 256) { sWq[t] = Wq[t]; sWk[t] = Wk[t]; }
    for (int t = tid; t < Cn*Cn; t += 256) sWv[t] = Wv[t];
    if (tid < CQ) { sbq[tid] = bq[tid]; sbk[tid] = bk[tid]; }
    if (tid < Cn) sbv[tid] = bv[tid];
    __syncthreads();
    int pos = blockIdx.x * 256 + tid;           // pos = b*L + l
    int b = pos / Ln, l = pos % Ln;
    float xc[Cn];
    for (int c = 0; c < Cn; c++) xc[c] = x[(b*Cn + c)*Ln + l];
    for (int o = 0; o < CQ; o++) {
        float sq = sbq[o], sk = sbk[o];
        for (int c = 0; c < Cn; c++) { sq += sWq[o*Cn+c]*xc[c]; sk += sWk[o*Cn+c]*xc[c]; }
        qo[pos*CQ + o] = sq;
        ko[pos*CQ + o] = sk;
    }
    for (int o = 0; o < Cn; o++) {
        float sv = sbv[o];
        for (int c = 0; c < Cn; c++) sv += sWv[o*Cn+c]*xc[c];
        vo[pos*Cn + o] = sv;
    }
}

__global__ void count_kernel(const int* __restrict__ hidx, int* cnt) {
    int t = blockIdx.x * 256 + threadIdx.x;     // over B*NH*L
    int bh = t / Ln;
    atomicAdd(&cnt[bh*NB + hidx[t]], 1);
}

__global__ void scan_kernel(const int* __restrict__ cnt, int* st, int* cur) {
    int bh = blockIdx.x;
    if (threadIdx.x == 0) {
        int run = 0;
        for (int u = 0; u < NB; u++) {
            st[bh*NB + u] = run;
            cur[bh*NB + u] = run;
            run += cnt[bh*NB + u];
        }
    }
}

__global__ void scatter_kernel(const int* __restrict__ hidx, int* cur, int* mem) {
    int t = blockIdx.x * 256 + threadIdx.x;
    int bh = t / Ln, l = t % Ln;
    int slot = atomicAdd(&cur[bh*NB + hidx[t]], 1);
    mem[bh*Ln + slot] = l;
}

__global__ __launch_bounds__(256) void attn_kernel(
        const float* __restrict__ q, const float* __restrict__ k,
        const float* __restrict__ v, const int* __restrict__ cnt,
        const int* __restrict__ st, const int* __restrict__ mem,
        float* __restrict__ acc) {
    __shared__ int   mem_s[CH];
    __shared__ float ks[CH*CQ];
    __shared__ float vs[CH*Cn];
    int blk = blockIdx.x;
    int b = blk / (NH*NB);
    int rem = blk % (NH*NB);
    int h = rem / NB, u = rem % NB;
    int bh = b*NH + h;
    int S = cnt[bh*NB + u];
    int base = bh*Ln + st[bh*NB + u];
    int tid = threadIdx.x;

    for (int qb = 0; qb < S; qb += 256) {
        int qi = qb + tid;
        bool active = qi < S;
        int iq = 0;
        float qr[CQ];
        float m = -1e30f, lsum = 0.f;
        float o[Cn];
        for (int c = 0; c < CQ; c++) qr[c] = 0.f;
        for (int c = 0; c < Cn; c++) o[c] = 0.f;
        if (active) {
            iq = mem[base + qi];
            const float* qp = &q[(b*Ln + iq)*CQ];
            for (int c = 0; c < CQ; c++) qr[c] = qp[c];
        }
        for (int c0 = 0; c0 < S; c0 += CH) {
            int n = min(CH, S - c0);
            __syncthreads();   // previous chunk's LDS reads done
            for (int t = tid; t < n; t += 256) mem_s[t] = mem[base + c0 + t];
            __syncthreads();
            for (int t = tid; t < n*CQ; t += 256) {
                int j = t / CQ, c = t % CQ;
                ks[t] = k[(b*Ln + mem_s[j])*CQ + c];
            }
            for (int t = tid; t < n*Cn; t += 256) {
                int j = t / Cn, c = t % Cn;
                vs[t] = v[(b*Ln + mem_s[j])*Cn + c];
            }
            __syncthreads();
            if (active) {
                for (int j = 0; j < n; j++) {
                    const float* kp = &ks[j*CQ];
                    float s = 0.f;
                    for (int c = 0; c < CQ; c++) s += qr[c]*kp[c];
                    const float* vp = &vs[j*Cn];
                    if (s <= m) {
                        float p = __expf(s - m);
                        lsum += p;
                        for (int c = 0; c < Cn; c++) o[c] += p*vp[c];
                    } else {
                        float sc = __expf(m - s);
                        m = s;
                        lsum = lsum*sc + 1.f;
                        for (int c = 0; c < Cn; c++) o[c] = o[c]*sc + vp[c];
                    }
                }
            }
        }
        if (active) {
            float inv = 1.f / lsum;
            float* ap = &acc[(b*Ln + iq)*Cn];
            for (int c = 0; c < Cn; c++) atomicAdd(&ap[c], o[c]*inv);
        }
    }
}

__global__ void outconv_kernel(const float* __restrict__ acc,
                               const float* __restrict__ Wo, const float* __restrict__ bo,
                               const float* __restrict__ gamma,
                               const float* __restrict__ x, float* __restrict__ y) {
    __shared__ float sW[Cn*Cn];
    __shared__ float sb[Cn];
    int tid = threadIdx.x;
    for (int t = tid; t < Cn*Cn; t += 256) sW[t] = Wo[t];
    if (tid < Cn) sb[tid] = bo[tid];
    __syncthreads();
    float g = gamma[0];
    int pos = blockIdx.x * 256 + tid;           // pos = b*L + l
    int b = pos / Ln, l = pos % Ln;
    float a[Cn];
    const float* ap = &acc[pos*Cn];
    for (int c = 0; c < Cn; c++) a[c] = ap[c] * 0.25f;  // / n_hashes
    for (int o = 0; o < Cn; o++) {
        float s = sb[o];
        for (int c = 0; c < Cn; c++) s += sW[o*Cn+c]*a[c];
        y[(b*Cn + o)*Ln + l] = g*s + x[(b*Cn + o)*Ln + l];
    }
}

__global__ void stats_kernel(const float* __restrict__ y,
                             float* __restrict__ mean, float* __restrict__ istd) {
    int c = blockIdx.x;
    int tid = threadIdx.x;
    float s = 0.f, s2 = 0.f;
    for (int t = tid; t < Bn*Ln; t += 256) {
        int b = t / Ln, l = t % Ln;
        float vv = y[(b*Cn + c)*Ln + l];
        s += vv; s2 += vv*vv;
    }
    __shared__ float rs[256], rs2[256];
    rs[tid] = s; rs2[tid] = s2;
    __syncthreads();
    for (int w = 128; w > 0; w >>= 1) {
        if (tid < w) { rs[tid] += rs[tid+w]; rs2[tid] += rs2[tid+w]; }
        __syncthreads();
    }
    if (tid == 0) {
        float mu = rs[0] / (float)(Bn*Ln);
        float var = rs2[0] / (float)(Bn*Ln) - mu*mu;
        mean[c] = mu;
        istd[c] = rsqrtf(var + EPSV);
    }
}

__global__ void norm_kernel(const float* __restrict__ y,
                            const float* __restrict__ mean, const float* __restrict__ istd,
                            const float* __restrict__ bnw, const float* __restrict__ bnb,
                            float* __restrict__ out) {
    int t = blockIdx.x * 256 + threadIdx.x;
    int c = (t / Ln) % Cn;
    out[t] = (y[t] - mean[c]) * istd[c] * bnw[c] + bnb[c];
}

extern "C" void kernel_launch(void* const* d_in, const int* in_sizes, int n_in,
                              void* d_out, int out_size, void* d_ws, size_t ws_size,
                              hipStream_t stream) {
    const float* x    = (const float*)d_in[0];
    const int*   hidx = (const int*)  d_in[1];
    const float* Wq   = (const float*)d_in[2];
    const float* bq   = (const float*)d_in[3];
    const float* Wk   = (const float*)d_in[4];
    const float* bk   = (const float*)d_in[5];
    const float* Wv   = (const float*)d_in[6];
    const float* bv   = (const float*)d_in[7];
    const float* Wo   = (const float*)d_in[8];
    const float* bo   = (const float*)d_in[9];
    const float* gam  = (const float*)d_in[10];
    const float* bnw  = (const float*)d_in[11];
    const float* bnb  = (const float*)d_in[12];
    float* out = (float*)d_out;

    float* ws = (float*)d_ws;
    float* q    = ws + OFF_Q;
    float* k    = ws + OFF_K;
    float* v    = ws + OFF_V;
    float* acc  = ws + OFF_ACC;
    float* y    = ws + OFF_Y;
    int*   cnt  = (int*)(ws + OFF_CNT);
    int*   st   = (int*)(ws + OFF_ST);
    int*   cur  = (int*)(ws + OFF_CUR);
    int*   mem  = (int*)(ws + OFF_MEM);
    float* mean = ws + OFF_MEAN;
    float* istd = ws + OFF_ISTD;

    hipMemsetAsync(cnt, 0, Bn*NH*NB*sizeof(int), stream);
    hipMemsetAsync(acc, 0, (size_t)Bn*Ln*Cn*sizeof(float), stream);

    qkv_kernel<<<Bn*Ln/256, 256, 0, stream>>>(x, Wq, bq, Wk, bk, Wv, bv, q, k, v);
    count_kernel<<<Bn*NH*Ln/256, 256, 0, stream>>>(hidx, cnt);
    scan_kernel<<<Bn*NH, 64, 0, stream>>>(cnt, st, cur);
    scatter_kernel<<<Bn*NH*Ln/256, 256, 0, stream>>>(hidx, cur, mem);
    attn_kernel<<<Bn*NH*NB, 256, 0, stream>>>(q, k, v, cnt, st, mem, acc);
    outconv_kernel<<<Bn*Ln/256, 256, 0, stream>>>(acc, Wo, bo, gam, x, y);
    stats_kernel<<<Cn, 256, 0, stream>>>(y, mean, istd);
    norm_kernel<<<Bn*Cn*Ln/256, 256, 0, stream>>>(y, mean, istd, bnw, bnb, out);
}